// Round 14
// baseline (4542.002 us; speedup 1.0000x reference)
//
#include <hip/hip_runtime.h>

typedef _Float16 f16;
typedef f16  f16x8 __attribute__((ext_vector_type(8)));
typedef float f32x4 __attribute__((ext_vector_type(4)));
typedef unsigned int u32;
typedef unsigned short u16;
typedef unsigned long long u64;

// Problem dims
#define NB   32
#define NT   512
#define NM   6
#define NH   512
#define NH3  1536
#define PADTOK 1
#define LO_SCALE 4096.0f
#define LO_INV   (1.0f/4096.0f)

// ws layout (bytes):
//  A2    [16448][1024] f16 : 33,685,504 @ 0  (rows 0..16383 outs b*T+t, 16384..16415 hidden, 16416+ zeroed)
//  Ahi   [16384][512] f16 @ 0 (ALIASES A2 -- dead before k_recur writes A2); Alo @ 16,777,216
//  xs2_f [512 t][32 s][4 g][32 b][16 c] f16 @ 33,685,504 (67,108,864)   g: z,r,h,hlo -- 4KB/(t,s) blob
//  xs2_b same @ 100,794,368
//  hb    [2 dir][RING planes][32 s][32 b][16 c] f16 @ 167,903,232
//        WRITE-ONCE ring (R12-proven): plane p written once, read once per launch ->
//        plain cached consumer loads are stale-proof (first touch gated by that slice's flag).
//  flags [2 d][32 s][544] u32 after hb -- write-once 0->1 per launch (R12-proven protocol)
#define XS2F_OFF  33685504
#define XS2B_OFF  100794368
#define HB_OFF    167903232
#define SLOT_STRIDE 544
#define FLAGS_U32 (2 * 32 * SLOT_STRIDE)   // 34816
#define PLANE_E   16384                    // u16 elems per plane (32KB)

// producer-side device-scope store (L1/L2 bypass to MALL) -- R6/R9/R12-proven class
__device__ __forceinline__ void coh_store_u32(u32* base, u32 voff, u32 val) {
  asm volatile("global_store_dword %0, %1, %2 sc0 sc1"
               :: "v"(voff), "v"(val), "s"(base) : "memory");
}

// ---------------- embedding + flag zeroing ----------------
__global__ __launch_bounds__(128) void k_embed(const int* __restrict__ seqs,
                                               const float* __restrict__ emb,
                                               f16* __restrict__ Ahi,
                                               f16* __restrict__ Alo,
                                               f16* __restrict__ A2,
                                               u32* __restrict__ flags) {
  int row = blockIdx.x;           // b*NT + t
  int tid = threadIdx.x;          // 128
  if (row < 32) {                 // zero A2 pad rows 16416..16447
    for (int c2 = tid; c2 < 1024; c2 += 128)
      A2[(size_t)(16416 + row) * 1024 + c2] = (f16)0.f;
  }
  if (row < 64) {                 // zero flag slots (every launch, graph-replay safe)
    for (int j = row * 128 + tid; j < FLAGS_U32; j += 64 * 128)
      flags[j] = 0u;
  }
  const int* tr = seqs + (size_t)row * NM;
  int c0 = tid * 4;
  float acc0 = 0.f, acc1 = 0.f, acc2 = 0.f, acc3 = 0.f;
  for (int m = 0; m < NM; m++) {
    int tk = tr[m];
    if (tk != PADTOK) {
      float4 ev = *(const float4*)(emb + (size_t)tk * NH + c0);
      acc0 += ev.x; acc1 += ev.y; acc2 += ev.z; acc3 += ev.w;
    }
  }
  float a[4] = {acc0, acc1, acc2, acc3};
  for (int j = 0; j < 4; j++) {
    float v = a[j];
    f16 h = (f16)v;
    float lo = (v - (float)h) * LO_SCALE;
    Ahi[(size_t)row * NH + c0 + j] = h;
    Alo[(size_t)row * NH + c0 + j] = (f16)lo;
  }
}

// ---------------- input GEMM: xs2 = emb @ kernel + b_in, slice-blocked blob layout ----------------
__global__ __launch_bounds__(256) void k_gemm_in(const f16* __restrict__ Ahi,
                                                 const f16* __restrict__ Alo,
                                                 const float* __restrict__ Bw,    // [512][1536]
                                                 const float* __restrict__ bias,  // b[0][1536]
                                                 f16* __restrict__ xs2) {         // [512][32][4][32][16]
  __shared__ f16 BsH[64][40];
  __shared__ f16 BsL[64][40];
  int bx = blockIdx.x, by = blockIdx.y;
  int tid = threadIdx.x;
  int w = tid >> 6, l = tid & 63;
  int row0 = bx * 64 + w * 16;
  int col0 = by * 64;
  int arow = row0 + (l & 15);
  int kg = (l >> 4) * 8;
  f32x4 acc[4], accs[4];
  for (int nt = 0; nt < 4; nt++) {
    float bv = bias[col0 + nt * 16 + (l & 15)];
    f32x4 t = {bv, bv, bv, bv};
    acc[nt] = t;
    f32x4 z = {0.f, 0.f, 0.f, 0.f};
    accs[nt] = z;
  }
  for (int kb = 0; kb < NH; kb += 32) {
    __syncthreads();
    for (int idx = tid; idx < 2048; idx += 256) {
      int n = idx & 63, kl = idx >> 6;
      float v = Bw[(size_t)(kb + kl) * NH3 + col0 + n];
      f16 h = (f16)v;
      BsH[n][kl] = h;
      BsL[n][kl] = (f16)((v - (float)h) * LO_SCALE);
    }
    __syncthreads();
    f16x8 ah = *(const f16x8*)(Ahi + (size_t)arow * NH + kb + kg);
    f16x8 al = *(const f16x8*)(Alo + (size_t)arow * NH + kb + kg);
    for (int nt = 0; nt < 4; nt++) {
      f16x8 bh = *(const f16x8*)(&BsH[nt * 16 + (l & 15)][kg]);
      f16x8 bl = *(const f16x8*)(&BsL[nt * 16 + (l & 15)][kg]);
      acc[nt]  = __builtin_amdgcn_mfma_f32_16x16x32_f16(ah, bh, acc[nt], 0, 0, 0);
      accs[nt] = __builtin_amdgcn_mfma_f32_16x16x32_f16(al, bh, accs[nt], 0, 0, 0);
      accs[nt] = __builtin_amdgcn_mfma_f32_16x16x32_f16(ah, bl, accs[nt], 0, 0, 0);
    }
  }
  for (int nt = 0; nt < 4; nt++)
    for (int r = 0; r < 4; r++) {
      int grow = row0 + (l >> 4) * 4 + r;          // = b*NT + t
      int b = grow >> 9, t = grow & (NT - 1);
      int gcol = col0 + nt * 16 + (l & 15);
      int g = gcol >> 9, u = gcol & 511;
      int ss = u >> 4, cc = u & 15;
      float v = acc[nt][r] + accs[nt][r] * LO_INV;
      f16 h = (f16)v;
      size_t idx = (size_t)(t * 32 + ss) * 2048 + g * 512 + b * 16 + cc;
      xs2[idx] = h;
      if (g == 2)                                   // xh lo channel -> g=3 slot
        xs2[idx + 512] = (f16)(v - (float)h);
    }
}

// ---------------- recurrence (plain launch, 64 wgs, 1/CU) ----------------
// dir = wg>>5, slice = wg&31. rk slice hi/lo in LDS (96KB).
// R12 block-level protocol (proven): sc0sc1 packed stores + per-wave ack +
// one __syncthreads + tid0 flag. NEW: ballot-driven INCREMENTAL consumption --
// fragment kk is consumed as soon as its two producer slices (2kk, 2kk+1)
// publish, hiding producer skew and load latency under MFMA.
__global__ __launch_bounds__(128) void k_recur(const f16* __restrict__ xs2_f,
                                               const f16* __restrict__ xs2_b,
                                               const float* __restrict__ rk_f,
                                               const float* __restrict__ rk_b,
                                               const float* __restrict__ b_f,
                                               const float* __restrict__ b_b,
                                               const int* __restrict__ lens,
                                               u16* __restrict__ hb_f,
                                               u16* __restrict__ hb_b,
                                               f16* __restrict__ A2,
                                               u32* __restrict__ flags,
                                               int ring_mask) {
  __shared__ f16 WsH[48 * 512];   // [n][k] XOR-swizzled, hi
  __shared__ f16 WsL[48 * 512];   // lo * 2^12
  int wg = blockIdx.x;
  int d = wg >> 5;
  int s = wg & 31;
  int u0 = s * 16;
  int tid = threadIdx.x;
  int wv = tid >> 6, l = tid & 63;
  const f16*   xs2 = d ? xs2_b : xs2_f;
  u16*         myhb = d ? hb_b : hb_f;
  const float* rk = d ? rk_b : rk_f;
  const float* bb = d ? b_b  : b_f;

  for (int idx = tid; idx < 48 * 512; idx += 128) {
    int k = idx / 48, n = idx % 48;
    int gcol = (n >> 4) * NH + u0 + (n & 15);
    float v = rk[(size_t)k * NH3 + gcol];
    f16 h = (f16)v;
    f16 lo = (f16)((v - (float)h) * LO_SCALE);
    int byte = (n * 1024 + k * 2) ^ ((n & 7) << 4);
    *(f16*)((char*)WsH + byte) = h;
    *(f16*)((char*)WsL + byte) = lo;
  }
  __syncthreads();   // Ws read-only hereafter

  int c = l & 15;
  float brz = bb[NH3 + 0 * NH + u0 + c];
  float brr = bb[NH3 + 1 * NH + u0 + c];
  float brh = bb[NH3 + 2 * NH + u0 + c];
  int mrow[4], lenv[4];
  float hstate[4];
  u32 vo32[4];                     // byte offset of the u32 pair {c_even, c_odd}
  for (int r = 0; r < 4; r++) {
    int b = wv * 16 + (l >> 4) * 4 + r;
    mrow[r] = b;
    lenv[r] = lens[b];
    hstate[r] = 0.f;
    vo32[r] = (u32)(s * 1024 + b * 32 + (c & ~1) * 2);
  }
  const int fbase = (d * 32 + s) * SLOT_STRIDE;
  // h0 = 0 into plane 0 (u32-packed, even lanes); ack; publish slot 0
  for (int r = 0; r < 4; r++)
    if ((l & 1) == 0)
      coh_store_u32((u32*)myhb, vo32[r], 0u);
  asm volatile("s_waitcnt vmcnt(0)" ::: "memory");
  __syncthreads();
  if (tid == 0)
    __hip_atomic_store(&flags[fbase + 0], 1u,
                       __ATOMIC_RELAXED, __HIP_MEMORY_SCOPE_AGENT);

  int arow_b = wv * 16 + (l & 15);
  int kg = (l >> 4) * 8;
  int cbase = c * 1024;
  int zc = (c & 7) << 4;
  // per-lane base inside a plane for A-fragment reads:
  // cols C=kk*32+kg -> slice C>>4 (1KB block), col C&15
  int hbase_lane = (kg >> 4) * 1024 + arow_b * 32 + (kg & 15) * 2;
  const u32* myflags = flags + d * 32 * SLOT_STRIDE + (l & 31) * SLOT_STRIDE;

#pragma unroll 1
  for (int i = 0; i < NT; i++) {
    int t = d ? (NT - 1 - i) : i;
    const u16* hplane = myhb + (size_t)(i & ring_mask) * PLANE_E;
    u32* wplane32 = (u32*)(myhb + (size_t)((i + 1) & ring_mask) * PLANE_E);

    // xs blob loads issued first (first USE is in the epilogue -> latency hides)
    const u16* sl = (const u16*)(xs2 + (size_t)(t * 32 + s) * 2048);
    u16 rxz[4], rxr[4], rxh[4], rxl[4];
#pragma unroll
    for (int r = 0; r < 4; r++) {
      int bo = mrow[r] * 16 + c;
      rxz[r] = sl[bo];
      rxr[r] = sl[512 + bo];
      rxh[r] = sl[1024 + bo];
      rxl[r] = sl[1536 + bo];
    }

    f32x4 a0, a1, a2, s0, s1, s2;
#pragma unroll
    for (int r = 0; r < 4; r++) {
      a0[r] = 0.f; a1[r] = 0.f; a2[r] = 0.f;
      s0[r] = 0.f; s1[r] = 0.f; s2[r] = 0.f;
    }

    // ---- ballot-driven incremental consumption ----
    // lane (l&31) polls slice (l&31)'s flag; ballot -> wave-uniform ready mask;
    // consume kk as soon as slices 2kk and 2kk+1 are both ready.
    u32 sready = 0;          // bit s: slice s published step i
    u32 pend = 0xFFFFu;      // bit kk: fragment kk not yet consumed
    do {
      u32 fl = 1u;
      if (!((sready >> (l & 31)) & 1u))
        fl = __hip_atomic_load(myflags + i, __ATOMIC_RELAXED, __HIP_MEMORY_SCOPE_AGENT);
      u64 ball = __ballot(fl != 0u);
      sready |= (u32)ball;   // lanes 0..31 carry slice states (lanes 32..63 poll same slices)
      asm volatile("" ::: "memory");  // no hoisting of plane loads above the poll
#pragma unroll
      for (int kk = 0; kk < 16; kk++) {
        if ((pend >> kk) & 1u) {
          if (((sready >> (2 * kk)) & 1u) && ((sready >> (2 * kk + 1)) & 1u)) {
            pend &= ~(1u << kk);
            f16x8 ah = *(const f16x8*)((const char*)hplane + hbase_lane + kk * 2048);
            int kb2 = (kk * 32 + kg) * 2;
            int off = (cbase + kb2) ^ zc;
            f16x8 b0h = *(const f16x8*)((const char*)WsH + off);
            f16x8 b1h = *(const f16x8*)((const char*)WsH + 16384 + off);
            f16x8 b2h = *(const f16x8*)((const char*)WsH + 32768 + off);
            f16x8 b0l = *(const f16x8*)((const char*)WsL + off);
            f16x8 b1l = *(const f16x8*)((const char*)WsL + 16384 + off);
            f16x8 b2l = *(const f16x8*)((const char*)WsL + 32768 + off);
            a0 = __builtin_amdgcn_mfma_f32_16x16x32_f16(ah, b0h, a0, 0, 0, 0);
            s0 = __builtin_amdgcn_mfma_f32_16x16x32_f16(ah, b0l, s0, 0, 0, 0);
            a1 = __builtin_amdgcn_mfma_f32_16x16x32_f16(ah, b1h, a1, 0, 0, 0);
            s1 = __builtin_amdgcn_mfma_f32_16x16x32_f16(ah, b1l, s1, 0, 0, 0);
            a2 = __builtin_amdgcn_mfma_f32_16x16x32_f16(ah, b2h, a2, 0, 0, 0);
            s2 = __builtin_amdgcn_mfma_f32_16x16x32_f16(ah, b2l, s2, 0, 0, 0);
          }
        }
      }
    } while (pend);

    u16 hu[4];
#pragma unroll
    for (int r = 0; r < 4; r++) {
      union { u16 u; f16 f; } uz, ur, uh, ul;
      uz.u = rxz[r]; ur.u = rxr[r]; uh.u = rxh[r]; ul.u = rxl[r];
      float az = a0[r] + s0[r] * LO_INV + (float)uz.f + brz;
      float ar = a1[r] + s1[r] * LO_INV + (float)ur.f + brr;
      float ahg = a2[r] + s2[r] * LO_INV;
      float xh = (float)uh.f + (float)ul.f;
      float z  = 1.f / (1.f + __expf(-az));
      float rr = 1.f / (1.f + __expf(-ar));
      float hh = tanhf(xh + rr * (ahg + brh));
      float hn = z * hstate[r] + (1.f - z) * hh;
      bool msk = t < lenv[r];
      hn = msk ? hn : hstate[r];
      hstate[r] = hn;
      union { f16 f; u16 u; } chv;
      chv.f = (f16)hn;
      hu[r] = chv.u;
    }
    // pack lane pairs {c, c+1} into u32; even lanes store (halved MALL store txns)
#pragma unroll
    for (int r = 0; r < 4; r++) {
      u32 other = (u32)__shfl_xor((int)hu[r], 1);
      if ((l & 1) == 0)
        coh_store_u32(wplane32, vo32[r], (u32)hu[r] | (other << 16));
    }
    // per-wave ack + block barrier, then tid0 publishes; A2 off the critical path
    asm volatile("s_waitcnt vmcnt(0)" ::: "memory");
    __syncthreads();
    if (tid == 0)
      __hip_atomic_store(&flags[fbase + i + 1], 1u,
                         __ATOMIC_RELAXED, __HIP_MEMORY_SCOPE_AGENT);
#pragma unroll
    for (int r = 0; r < 4; r++)
      A2[((size_t)mrow[r] * NT + t) * 1024 + d * NH + u0 + c] = (f16)hstate[r];
  }
  for (int r = 0; r < 4; r++)
    A2[(size_t)(16384 + mrow[r]) * 1024 + d * NH + u0 + c] = (f16)hstate[r];
}

// ---------------- output projection ----------------
__global__ __launch_bounds__(256) void k_gemm_out(const f16* __restrict__ A2,   // [16448][1024]
                                                  const float* __restrict__ Wk, // [1024][512]
                                                  const float* __restrict__ Wb, // [512]
                                                  float* __restrict__ Out) {    // [16416][512]
  __shared__ f16 Bs[64][40];
  int bx = blockIdx.x, by = blockIdx.y;
  int tid = threadIdx.x;
  int w = tid >> 6, l = tid & 63;
  int row0 = bx * 64 + w * 16;
  int col0 = by * 64;
  int arow = row0 + (l & 15);
  int kg = (l >> 4) * 8;
  f32x4 acc[4];
  for (int nt = 0; nt < 4; nt++) {
    float bv = Wb[col0 + nt * 16 + (l & 15)];
    f32x4 t = {bv, bv, bv, bv};
    acc[nt] = t;
  }
  for (int kb = 0; kb < 1024; kb += 32) {
    __syncthreads();
    for (int idx = tid; idx < 2048; idx += 256) {
      int n = idx & 63, kl = idx >> 6;
      Bs[n][kl] = (f16)Wk[(size_t)(kb + kl) * NH + col0 + n];
    }
    __syncthreads();
    f16x8 av = *(const f16x8*)(A2 + (size_t)arow * 1024 + kb + kg);
    for (int nt = 0; nt < 4; nt++) {
      f16x8 bv = *(const f16x8*)(&Bs[nt * 16 + (l & 15)][kg]);
      acc[nt] = __builtin_amdgcn_mfma_f32_16x16x32_f16(av, bv, acc[nt], 0, 0, 0);
    }
  }
  for (int nt = 0; nt < 4; nt++)
    for (int r = 0; r < 4; r++) {
      int grow = row0 + (l >> 4) * 4 + r;
      if (grow < 16416)
        Out[(size_t)grow * NH + col0 + nt * 16 + (l & 15)] = acc[nt][r];
    }
}

extern "C" void kernel_launch(void* const* d_in, const int* in_sizes, int n_in,
                              void* d_out, int out_size, void* d_ws, size_t ws_size,
                              hipStream_t stream) {
  (void)in_sizes; (void)n_in; (void)out_size;
  const int*   seqs = (const int*)d_in[0];
  const int*   lens = (const int*)d_in[1];
  const float* emb  = (const float*)d_in[2];
  const float* k_f  = (const float*)d_in[3];
  const float* rk_f = (const float*)d_in[4];
  const float* b_f  = (const float*)d_in[5];
  const float* k_b  = (const float*)d_in[6];
  const float* rk_b = (const float*)d_in[7];
  const float* b_b  = (const float*)d_in[8];
  const float* Wk   = (const float*)d_in[9];
  const float* Wb   = (const float*)d_in[10];
  float* out = (float*)d_out;
  char* ws = (char*)d_ws;
  f16* A2     = (f16*)(ws + 0);
  f16* Ahi    = (f16*)(ws + 0);            // aliases A2; dead before A2 written
  f16* Alo    = (f16*)(ws + 16777216);
  f16* xs2_f  = (f16*)(ws + XS2F_OFF);
  f16* xs2_b  = (f16*)(ws + XS2B_OFF);

  // ring depth: 512 (fully write-once) if ws fits, else 64
  int ring = 512;
  size_t need512 = (size_t)HB_OFF + 2ull * 512 * 32768 + (size_t)FLAGS_U32 * 4;
  if (ws_size < need512) ring = 64;
  u16* hb_f = (u16*)(ws + HB_OFF);
  u16* hb_b = hb_f + (size_t)ring * PLANE_E;
  u32* flags = (u32*)(ws + HB_OFF + 2ull * ring * 32768);
  int ring_mask = ring - 1;

  hipLaunchKernelGGL(k_embed, dim3(16384), dim3(128), 0, stream, seqs, emb, Ahi, Alo, A2, flags);
  hipLaunchKernelGGL(k_gemm_in, dim3(256, 24), dim3(256), 0, stream, Ahi, Alo, k_f, b_f, xs2_f);
  hipLaunchKernelGGL(k_gemm_in, dim3(256, 24), dim3(256), 0, stream, Ahi, Alo, k_b, b_b, xs2_b);
  hipLaunchKernelGGL(k_recur, dim3(64), dim3(128), 0, stream,
                     xs2_f, xs2_b, rk_f, rk_b, b_f, b_b, lens, hb_f, hb_b, A2, flags, ring_mask);
  hipLaunchKernelGGL(k_gemm_out, dim3(257, 8), dim3(256), 0, stream, A2, Wk, Wb, out);
}

// Round 15
// 3765.089 us; speedup vs baseline: 1.2063x; 1.2063x over previous
//
#include <hip/hip_runtime.h>

typedef _Float16 f16;
typedef f16  f16x8 __attribute__((ext_vector_type(8)));
typedef float f32x4 __attribute__((ext_vector_type(4)));
typedef unsigned int u32;
typedef unsigned short u16;

// Problem dims
#define NB   32
#define NT   512
#define NM   6
#define NH   512
#define NH3  1536
#define PADTOK 1
#define LO_SCALE 4096.0f
#define LO_INV   (1.0f/4096.0f)

// ws layout (bytes):
//  A2    [16448][1024] f16 : 33,685,504 @ 0  (rows 0..16383 outs b*T+t, 16384..16415 hidden, 16416+ zeroed)
//  Ahi   [16384][512] f16 @ 0 (ALIASES A2 -- dead before k_recur writes A2); Alo @ 16,777,216
//  xs2_f [512 t][32 s][4 g][32 b][16 c] f16 @ 33,685,504 (67,108,864)   g: z,r,h,hlo -- 4KB/(t,s) blob
//  xs2_b same @ 100,794,368
//  hb    [2 dir][RING planes][32 s][32 b][16 c] f16 @ 167,903,232
//        WRITE-ONCE ring (R12-proven): plane p written once, read once per launch ->
//        plain cached consumer loads are stale-proof. Each 128B line: ONE producer slice.
//  flags [2 d][32 s][544] u32 after hb -- write-once 0->1, slice-major (R12-proven)
#define XS2F_OFF  33685504
#define XS2B_OFF  100794368
#define HB_OFF    167903232
#define SLOT_STRIDE 544
#define FLAGS_U32 (2 * 32 * SLOT_STRIDE)   // 34816
#define PLANE_E   16384                    // u16 elems per plane (32KB)

// producer-side device-scope store (L1/L2 bypass to MALL) -- R6/R9/R12-proven class
__device__ __forceinline__ void coh_store_u16(u16* base, u32 voff, u32 val) {
  asm volatile("global_store_short %0, %1, %2 sc0 sc1"
               :: "v"(voff), "v"(val), "s"(base) : "memory");
}

// ---------------- embedding + flag zeroing ----------------
__global__ __launch_bounds__(128) void k_embed(const int* __restrict__ seqs,
                                               const float* __restrict__ emb,
                                               f16* __restrict__ Ahi,
                                               f16* __restrict__ Alo,
                                               f16* __restrict__ A2,
                                               u32* __restrict__ flags) {
  int row = blockIdx.x;           // b*NT + t
  int tid = threadIdx.x;          // 128
  if (row < 32) {                 // zero A2 pad rows 16416..16447
    for (int c2 = tid; c2 < 1024; c2 += 128)
      A2[(size_t)(16416 + row) * 1024 + c2] = (f16)0.f;
  }
  if (row < 64) {                 // zero flag slots (every launch, graph-replay safe)
    for (int j = row * 128 + tid; j < FLAGS_U32; j += 64 * 128)
      flags[j] = 0u;
  }
  const int* tr = seqs + (size_t)row * NM;
  int c0 = tid * 4;
  float acc0 = 0.f, acc1 = 0.f, acc2 = 0.f, acc3 = 0.f;
  for (int m = 0; m < NM; m++) {
    int tk = tr[m];
    if (tk != PADTOK) {
      float4 ev = *(const float4*)(emb + (size_t)tk * NH + c0);
      acc0 += ev.x; acc1 += ev.y; acc2 += ev.z; acc3 += ev.w;
    }
  }
  float a[4] = {acc0, acc1, acc2, acc3};
  for (int j = 0; j < 4; j++) {
    float v = a[j];
    f16 h = (f16)v;
    float lo = (v - (float)h) * LO_SCALE;
    Ahi[(size_t)row * NH + c0 + j] = h;
    Alo[(size_t)row * NH + c0 + j] = (f16)lo;
  }
}

// ---------------- input GEMM (both directions fused via blockIdx.z) ----------------
// xs2 = emb @ kernel + b_in, slice-blocked blob layout [512][32][4][32][16]
__global__ __launch_bounds__(256) void k_gemm_in(const f16* __restrict__ Ahi,
                                                 const f16* __restrict__ Alo,
                                                 const float* __restrict__ Bw_f,   // [512][1536]
                                                 const float* __restrict__ bias_f, // b_f[0][1536]
                                                 f16* __restrict__ xs2_f,
                                                 const float* __restrict__ Bw_b,
                                                 const float* __restrict__ bias_b,
                                                 f16* __restrict__ xs2_b) {
  const float* Bw   = blockIdx.z ? Bw_b   : Bw_f;
  const float* bias = blockIdx.z ? bias_b : bias_f;
  f16*         xs2  = blockIdx.z ? xs2_b  : xs2_f;
  __shared__ f16 BsH[64][40];
  __shared__ f16 BsL[64][40];
  int bx = blockIdx.x, by = blockIdx.y;
  int tid = threadIdx.x;
  int w = tid >> 6, l = tid & 63;
  int row0 = bx * 64 + w * 16;
  int col0 = by * 64;
  int arow = row0 + (l & 15);
  int kg = (l >> 4) * 8;
  f32x4 acc[4], accs[4];
  for (int nt = 0; nt < 4; nt++) {
    float bv = bias[col0 + nt * 16 + (l & 15)];
    f32x4 t = {bv, bv, bv, bv};
    acc[nt] = t;
    f32x4 z = {0.f, 0.f, 0.f, 0.f};
    accs[nt] = z;
  }
  for (int kb = 0; kb < NH; kb += 32) {
    __syncthreads();
    for (int idx = tid; idx < 2048; idx += 256) {
      int n = idx & 63, kl = idx >> 6;
      float v = Bw[(size_t)(kb + kl) * NH3 + col0 + n];
      f16 h = (f16)v;
      BsH[n][kl] = h;
      BsL[n][kl] = (f16)((v - (float)h) * LO_SCALE);
    }
    __syncthreads();
    f16x8 ah = *(const f16x8*)(Ahi + (size_t)arow * NH + kb + kg);
    f16x8 al = *(const f16x8*)(Alo + (size_t)arow * NH + kb + kg);
    for (int nt = 0; nt < 4; nt++) {
      f16x8 bh = *(const f16x8*)(&BsH[nt * 16 + (l & 15)][kg]);
      f16x8 bl = *(const f16x8*)(&BsL[nt * 16 + (l & 15)][kg]);
      acc[nt]  = __builtin_amdgcn_mfma_f32_16x16x32_f16(ah, bh, acc[nt], 0, 0, 0);
      accs[nt] = __builtin_amdgcn_mfma_f32_16x16x32_f16(al, bh, accs[nt], 0, 0, 0);
      accs[nt] = __builtin_amdgcn_mfma_f32_16x16x32_f16(ah, bl, accs[nt], 0, 0, 0);
    }
  }
  for (int nt = 0; nt < 4; nt++)
    for (int r = 0; r < 4; r++) {
      int grow = row0 + (l >> 4) * 4 + r;          // = b*NT + t
      int b = grow >> 9, t = grow & (NT - 1);
      int gcol = col0 + nt * 16 + (l & 15);
      int g = gcol >> 9, u = gcol & 511;
      int ss = u >> 4, cc = u & 15;
      float v = acc[nt][r] + accs[nt][r] * LO_INV;
      f16 h = (f16)v;
      size_t idx = (size_t)(t * 32 + ss) * 2048 + g * 512 + b * 16 + cc;
      xs2[idx] = h;
      if (g == 2)                                   // xh lo channel -> g=3 slot
        xs2[idx + 512] = (f16)(v - (float)h);
    }
}

// ---------------- recurrence (plain launch, 64 wgs, 1/CU) -- R12 verbatim ----------------
// dir = wg>>5, slice = wg&31. rk slice hi/lo in LDS (96KB).
// Producers: sc0sc1 f16 stores + vmcnt ack + write-once flags (R9-proven protocol).
// Consumers: PLAIN CACHED f16x8 loads from write-once ring planes (stale-proof).
__global__ __launch_bounds__(128) void k_recur(const f16* __restrict__ xs2_f,
                                               const f16* __restrict__ xs2_b,
                                               const float* __restrict__ rk_f,
                                               const float* __restrict__ rk_b,
                                               const float* __restrict__ b_f,
                                               const float* __restrict__ b_b,
                                               const int* __restrict__ lens,
                                               u16* __restrict__ hb_f,
                                               u16* __restrict__ hb_b,
                                               f16* __restrict__ A2,
                                               u32* __restrict__ flags,
                                               int ring_mask) {
  __shared__ f16 WsH[48 * 512];   // [n][k] XOR-swizzled, hi
  __shared__ f16 WsL[48 * 512];   // lo * 2^12
  int wg = blockIdx.x;
  int d = wg >> 5;
  int s = wg & 31;
  int u0 = s * 16;
  int tid = threadIdx.x;
  int w = tid >> 6, l = tid & 63;
  const f16*   xs2 = d ? xs2_b : xs2_f;
  u16*         myhb = d ? hb_b : hb_f;
  const float* rk = d ? rk_b : rk_f;
  const float* bb = d ? b_b  : b_f;

  for (int idx = tid; idx < 48 * 512; idx += 128) {
    int k = idx / 48, n = idx % 48;
    int gcol = (n >> 4) * NH + u0 + (n & 15);
    float v = rk[(size_t)k * NH3 + gcol];
    f16 h = (f16)v;
    f16 lo = (f16)((v - (float)h) * LO_SCALE);
    int byte = (n * 1024 + k * 2) ^ ((n & 7) << 4);
    *(f16*)((char*)WsH + byte) = h;
    *(f16*)((char*)WsL + byte) = lo;
  }
  __syncthreads();   // Ws read-only hereafter

  int c = l & 15;
  float brz = bb[NH3 + 0 * NH + u0 + c];
  float brr = bb[NH3 + 1 * NH + u0 + c];
  float brh = bb[NH3 + 2 * NH + u0 + c];
  int mrow[4], lenv[4];
  float hstate[4];
  u32 vo_h[4];                     // byte offset within a plane: s*1024 + b*32 + c*2
  for (int r = 0; r < 4; r++) {
    int b = w * 16 + (l >> 4) * 4 + r;
    mrow[r] = b;
    lenv[r] = lens[b];
    hstate[r] = 0.f;
    vo_h[r] = (u32)(s * 1024 + b * 32 + c * 2);
  }
  const int fbase = (d * 32 + s) * SLOT_STRIDE;
  // h0 = 0 into plane 0; ack; publish slot 0
  for (int r = 0; r < 4; r++)
    coh_store_u16(myhb, vo_h[r], 0u);
  asm volatile("s_waitcnt vmcnt(0)" ::: "memory");
  __syncthreads();
  if (tid == 0)
    __hip_atomic_store(&flags[fbase + 0], 1u,
                       __ATOMIC_RELAXED, __HIP_MEMORY_SCOPE_AGENT);

  int arow_b = w * 16 + (l & 15);
  int kg = (l >> 4) * 8;
  int cbase = c * 1024;
  int zc = (c & 7) << 4;
  // per-lane base inside a plane for A-fragment reads:
  // cols C=kk*32+kg -> slice C>>4 (block 1KB), col C&15
  int hbase_lane = (kg >> 4) * 1024 + arow_b * 32 + (kg & 15) * 2;

#pragma unroll 1
  for (int i = 0; i < NT; i++) {
    int t = d ? (NT - 1 - i) : i;
    const u16* hplane = myhb + (size_t)(i & ring_mask) * PLANE_E;
    u16* wplane = myhb + (size_t)((i + 1) & ring_mask) * PLANE_E;

    // wait: every slice of this direction has published h_i (write-once slot i)
    if (tid < 32) {
      const u32* fp = flags + (d * 32 + tid) * SLOT_STRIDE + i;
      while (__hip_atomic_load(fp, __ATOMIC_RELAXED, __HIP_MEMORY_SCOPE_AGENT) == 0u)
        __builtin_amdgcn_s_sleep(1);
    }
    __syncthreads();   // also a compiler memory barrier: h loads cannot hoist above

    // xs blob: contiguous 4KB for (t, s); plain cached
    const u16* sl = (const u16*)(xs2 + (size_t)(t * 32 + s) * 2048);
    u16 rxz[4], rxr[4], rxh[4], rxl[4];
#pragma unroll
    for (int r = 0; r < 4; r++) {
      int bo = mrow[r] * 16 + c;
      rxz[r] = sl[bo];
      rxr[r] = sl[512 + bo];
      rxh[r] = sl[1024 + bo];
      rxl[r] = sl[1536 + bo];
    }

    f32x4 a0, a1, a2, s0, s1, s2;
#pragma unroll
    for (int r = 0; r < 4; r++) {
      a0[r] = 0.f; a1[r] = 0.f; a2[r] = 0.f;
      s0[r] = 0.f; s1[r] = 0.f; s2[r] = 0.f;
    }
#pragma unroll
    for (int kk = 0; kk < 16; kk++) {
      f16x8 ah = *(const f16x8*)((const char*)hplane + hbase_lane + kk * 2048);
      int kb2 = (kk * 32 + kg) * 2;
      int off = (cbase + kb2) ^ zc;
      f16x8 b0h = *(const f16x8*)((const char*)WsH + off);
      f16x8 b1h = *(const f16x8*)((const char*)WsH + 16384 + off);
      f16x8 b2h = *(const f16x8*)((const char*)WsH + 32768 + off);
      f16x8 b0l = *(const f16x8*)((const char*)WsL + off);
      f16x8 b1l = *(const f16x8*)((const char*)WsL + 16384 + off);
      f16x8 b2l = *(const f16x8*)((const char*)WsL + 32768 + off);
      a0 = __builtin_amdgcn_mfma_f32_16x16x32_f16(ah, b0h, a0, 0, 0, 0);
      s0 = __builtin_amdgcn_mfma_f32_16x16x32_f16(ah, b0l, s0, 0, 0, 0);
      a1 = __builtin_amdgcn_mfma_f32_16x16x32_f16(ah, b1h, a1, 0, 0, 0);
      s1 = __builtin_amdgcn_mfma_f32_16x16x32_f16(ah, b1l, s1, 0, 0, 0);
      a2 = __builtin_amdgcn_mfma_f32_16x16x32_f16(ah, b2h, a2, 0, 0, 0);
      s2 = __builtin_amdgcn_mfma_f32_16x16x32_f16(ah, b2l, s2, 0, 0, 0);
    }

#pragma unroll
    for (int r = 0; r < 4; r++) {
      union { u16 u; f16 f; } uz, ur, uh, ul;
      uz.u = rxz[r]; ur.u = rxr[r]; uh.u = rxh[r]; ul.u = rxl[r];
      float az = a0[r] + s0[r] * LO_INV + (float)uz.f + brz;
      float ar = a1[r] + s1[r] * LO_INV + (float)ur.f + brr;
      float ahg = a2[r] + s2[r] * LO_INV;
      float xh = (float)uh.f + (float)ul.f;
      float z  = 1.f / (1.f + __expf(-az));
      float rr = 1.f / (1.f + __expf(-ar));
      float hh = tanhf(xh + rr * (ahg + brh));
      float hn = z * hstate[r] + (1.f - z) * hh;
      bool msk = t < lenv[r];
      hn = msk ? hn : hstate[r];
      hstate[r] = hn;
      union { f16 f; u16 u; } chv;
      chv.f = (f16)hn;
      coh_store_u16(wplane, vo_h[r], (u32)chv.u);
    }
    // ack h stores at device scope, then publish slot i+1; A2 off the critical path
    asm volatile("s_waitcnt vmcnt(0)" ::: "memory");
    __syncthreads();
    if (tid == 0)
      __hip_atomic_store(&flags[fbase + i + 1], 1u,
                         __ATOMIC_RELAXED, __HIP_MEMORY_SCOPE_AGENT);
#pragma unroll
    for (int r = 0; r < 4; r++)
      A2[((size_t)mrow[r] * NT + t) * 1024 + d * NH + u0 + c] = (f16)hstate[r];
  }
  for (int r = 0; r < 4; r++)
    A2[(size_t)(16384 + mrow[r]) * 1024 + d * NH + u0 + c] = (f16)hstate[r];
}

// ---------------- output projection ----------------
__global__ __launch_bounds__(256) void k_gemm_out(const f16* __restrict__ A2,   // [16448][1024]
                                                  const float* __restrict__ Wk, // [1024][512]
                                                  const float* __restrict__ Wb, // [512]
                                                  float* __restrict__ Out) {    // [16416][512]
  __shared__ f16 Bs[64][40];
  int bx = blockIdx.x, by = blockIdx.y;
  int tid = threadIdx.x;
  int w = tid >> 6, l = tid & 63;
  int row0 = bx * 64 + w * 16;
  int col0 = by * 64;
  int arow = row0 + (l & 15);
  int kg = (l >> 4) * 8;
  f32x4 acc[4];
  for (int nt = 0; nt < 4; nt++) {
    float bv = Wb[col0 + nt * 16 + (l & 15)];
    f32x4 t = {bv, bv, bv, bv};
    acc[nt] = t;
  }
  for (int kb = 0; kb < 1024; kb += 32) {
    __syncthreads();
    for (int idx = tid; idx < 2048; idx += 256) {
      int n = idx & 63, kl = idx >> 6;
      Bs[n][kl] = (f16)Wk[(size_t)(kb + kl) * NH + col0 + n];
    }
    __syncthreads();
    f16x8 av = *(const f16x8*)(A2 + (size_t)arow * 1024 + kb + kg);
    for (int nt = 0; nt < 4; nt++) {
      f16x8 bv = *(const f16x8*)(&Bs[nt * 16 + (l & 15)][kg]);
      acc[nt] = __builtin_amdgcn_mfma_f32_16x16x32_f16(av, bv, acc[nt], 0, 0, 0);
    }
  }
  for (int nt = 0; nt < 4; nt++)
    for (int r = 0; r < 4; r++) {
      int grow = row0 + (l >> 4) * 4 + r;
      if (grow < 16416)
        Out[(size_t)grow * NH + col0 + nt * 16 + (l & 15)] = acc[nt][r];
    }
}

extern "C" void kernel_launch(void* const* d_in, const int* in_sizes, int n_in,
                              void* d_out, int out_size, void* d_ws, size_t ws_size,
                              hipStream_t stream) {
  (void)in_sizes; (void)n_in; (void)out_size;
  const int*   seqs = (const int*)d_in[0];
  const int*   lens = (const int*)d_in[1];
  const float* emb  = (const float*)d_in[2];
  const float* k_f  = (const float*)d_in[3];
  const float* rk_f = (const float*)d_in[4];
  const float* b_f  = (const float*)d_in[5];
  const float* k_b  = (const float*)d_in[6];
  const float* rk_b = (const float*)d_in[7];
  const float* b_b  = (const float*)d_in[8];
  const float* Wk   = (const float*)d_in[9];
  const float* Wb   = (const float*)d_in[10];
  float* out = (float*)d_out;
  char* ws = (char*)d_ws;
  f16* A2     = (f16*)(ws + 0);
  f16* Ahi    = (f16*)(ws + 0);            // aliases A2; dead before A2 written
  f16* Alo    = (f16*)(ws + 16777216);
  f16* xs2_f  = (f16*)(ws + XS2F_OFF);
  f16* xs2_b  = (f16*)(ws + XS2B_OFF);

  // ring depth: 512 (fully write-once) if ws fits, else 64
  int ring = 512;
  size_t need512 = (size_t)HB_OFF + 2ull * 512 * 32768 + (size_t)FLAGS_U32 * 4;
  if (ws_size < need512) ring = 64;
  u16* hb_f = (u16*)(ws + HB_OFF);
  u16* hb_b = hb_f + (size_t)ring * PLANE_E;
  u32* flags = (u32*)(ws + HB_OFF + 2ull * ring * 32768);
  int ring_mask = ring - 1;

  hipLaunchKernelGGL(k_embed, dim3(16384), dim3(128), 0, stream, seqs, emb, Ahi, Alo, A2, flags);
  hipLaunchKernelGGL(k_gemm_in, dim3(256, 24, 2), dim3(256), 0, stream,
                     Ahi, Alo, k_f, b_f, xs2_f, k_b, b_b, xs2_b);
  hipLaunchKernelGGL(k_recur, dim3(64), dim3(128), 0, stream,
                     xs2_f, xs2_b, rk_f, rk_b, b_f, b_b, lens, hb_f, hb_b, A2, flags, ring_mask);
  hipLaunchKernelGGL(k_gemm_out, dim3(257, 8), dim3(256), 0, stream, A2, Wk, Wb, out);
}